// Round 8
// baseline (476.097 us; speedup 1.0000x reference)
//
#include <hip/hip_runtime.h>
#include <hip/hip_bf16.h>
#include <stdint.h>

typedef __hip_bfloat16 bf16;
typedef __attribute__((ext_vector_type(8))) short short8;
typedef __attribute__((ext_vector_type(4))) float f32x4;

#define BM 128
#define BN 128

__device__ __forceinline__ unsigned short f2bf_bits(float x) {
    return __builtin_bit_cast(unsigned short, __float2bfloat16(x));
}

// async global->LDS, 16B per lane, LDS dest = wave-uniform base + lane*16
__device__ __forceinline__ void gload_lds16(const bf16* g, bf16* l) {
    __builtin_amdgcn_global_load_lds(
        (const __attribute__((address_space(1))) void*)(const void*)g,
        (__attribute__((address_space(3))) void*)(void*)l,
        16, 0, 0);
}

// fused prep: [0,8192) feat->bf16 cvt; [8192,11264) W transpose+cvt; [11264] zero lsum
__global__ void prep_kernel(const float* __restrict__ feat, unsigned short* __restrict__ featb,
                            const float* __restrict__ W0, const float* __restrict__ W1,
                            const float* __restrict__ W2, bf16* __restrict__ Wt,
                            float* __restrict__ lsum) {
    const int b = blockIdx.x;
    const int tid = threadIdx.x;
    if (b < 8192) {
        int i = b * 256 + tid;
        float4 v = reinterpret_cast<const float4*>(feat)[i];
        ushort4 o;
        o.x = f2bf_bits(v.x); o.y = f2bf_bits(v.y);
        o.z = f2bf_bits(v.z); o.w = f2bf_bits(v.w);
        reinterpret_cast<ushort4*>(featb)[i] = o;
    } else if (b < 11264) {
        __shared__ float tile[32][33];
        const int b2 = b - 8192;
        const int z = b2 >> 10;
        const int t = b2 & 1023;
        const int bx = t & 31, by = t >> 5;
        const int tx = tid & 31, ty = tid >> 5;
        const float* in = (z == 0) ? W0 : (z == 1) ? W1 : W2;
        bf16* out = Wt + (size_t)z * 1024 * 1024;
        for (int r = ty; r < 32; r += 8)
            tile[r][tx] = in[(size_t)(by * 32 + r) * 1024 + bx * 32 + tx];
        __syncthreads();
        for (int r = ty; r < 32; r += 8)
            out[(size_t)(bx * 32 + r) * 1024 + by * 32 + tx] = __float2bfloat16(tile[tx][r]);
    } else {
        for (int i = tid; i < 8192; i += 256) lsum[i] = 0.f;
    }
}

// bf16 transpose: in [rows][cols] -> out [cols][rows]
__global__ void tpose_bf16(const bf16* __restrict__ in, bf16* __restrict__ out, int rows, int cols) {
    __shared__ bf16 tile[32][33];
    const int bx = blockIdx.x, by = blockIdx.y, tx = threadIdx.x;
    for (int r = threadIdx.y; r < 32; r += 8)
        tile[r][tx] = in[(size_t)(by * 32 + r) * cols + bx * 32 + tx];
    __syncthreads();
    for (int r = threadIdx.y; r < 32; r += 8)
        out[(size_t)(bx * 32 + r) * rows + by * 32 + tx] = tile[tx][r];
}

__global__ void scale_rows(float* __restrict__ out, const float* __restrict__ lsum) {
    int i = blockIdx.x * 256 + threadIdx.x;
    float4 v = reinterpret_cast<float4*>(out)[i];
    float inv = 1.0f / lsum[i >> 8];
    v.x *= inv; v.y *= inv; v.z *= inv; v.w *= inv;
    reinterpret_cast<float4*>(out)[i] = v;
}

// C[M][N] = A[M][K] * B[N][K]^T   (A row-stride = K, B row-stride = ldb)
// LDS tiles: KH stacked [128][32] half-tiles (64 B row stride, conflict-free b128).
// SWAP=1: blockIdx.x = N-tiles, blockIdx.y = M-tiles (chunked fallback O).
// SWAP=2: XCD-swizzled O grid (gridDim=(8, M/128[, z])): 8 col-tile blocks
//         sharing one P row-slab map to consecutive slots of ONE XCD.
// MODE 0: outb = C + bias[col]  (z-slab QKV), LDS-staged coalesced bf16 stores
// MODE 1: outb = exp(C*scale), atomicAdd row-sums -> lsum, LDS-staged stores
// MODE 2: outf += C                      (chunked O fallback, non-atomic)
// MODE 3: outf  = C / lsum[row]          (full-P O, single launch)
// MODE 4: atomicAdd(outf, C), split-K over blockIdx.z (K halved per block)
template <int MODE, int KH, int SWAP>
__global__ __launch_bounds__(256, 4)
void gemm_bt(const bf16* __restrict__ A, const bf16* __restrict__ B,
             const float* __restrict__ b0, const float* __restrict__ b1,
             const float* __restrict__ b2, float* __restrict__ lsum,
             bf16* __restrict__ outb, float* __restrict__ outf,
             int M, int N, int K, int ldb, int ldout, float scale) {
    constexpr int TILE = 128 * 32;
    constexpr int SELEMS = (2 * KH * TILE < 9216) ? 9216 : 2 * KH * TILE;
    __shared__ bf16 smem[SELEMS];
    bf16* As = smem;             // As + h*TILE
    bf16* Bs = smem + KH * TILE; // Bs + h*TILE

    const int tid  = threadIdx.x;
    const int lane = tid & 63;
    const int wave = tid >> 6;
    const int wm = wave & 1, wn = wave >> 1;
    const int l16  = lane & 15;
    const int quad = lane >> 4;
    long bm0, bn0;
    if (SWAP == 2) {
        const int lin = blockIdx.y * 8 + blockIdx.x;  // x fastest in dispatch order
        const int xcd = lin & 7;
        const int s   = lin >> 3;
        bn0 = (long)(s & 7) * BN;              // col tile 0..7
        bm0 = (long)((s >> 3) * 8 + xcd) * BM; // row tile, XCD-grouped
    } else {
        bm0 = (long)(SWAP ? blockIdx.y : blockIdx.x) * BM;
        bn0 = (long)(SWAP ? blockIdx.x : blockIdx.y) * BN;
    }

    const float* bias = nullptr;
    if (MODE == 0) {
        const int z = blockIdx.z;
        B    += (size_t)z * N * K;
        outb += (size_t)z * M * ldout;
        bias  = (z == 0) ? b0 : (z == 1) ? b1 : b2;
    }

    // split-K: MODE 4 covers [z*K/2, (z+1)*K/2)
    const int  ksp   = (MODE == 4) ? (K >> 1) : K;
    const long k0beg = (MODE == 4) ? (long)blockIdx.z * ksp : 0;

    // staging: per wave rows [wave*32, wave*32+32); u = 16-row slab, h = K-half.
    const int lrow = lane >> 2;
    const int lcol = (lane & 3) * 8;
    const bf16* gA[2][KH];
    const bf16* gB[2][KH];
    bf16* lA[2][KH];
    bf16* lB[2][KH];
#pragma unroll
    for (int u = 0; u < 2; u++)
#pragma unroll
        for (int h = 0; h < KH; h++) {
            gA[u][h] = A + (size_t)(bm0 + wave * 32 + u * 16 + lrow) * K + h * 32 + lcol;
            gB[u][h] = B + (size_t)(bn0 + wave * 32 + u * 16 + lrow) * ldb + h * 32 + lcol;
            lA[u][h] = As + h * TILE + (wave * 32 + u * 16) * 32;
            lB[u][h] = Bs + h * TILE + (wave * 32 + u * 16) * 32;
        }

    const bf16* Ard = As + (wm * 64 + l16) * 32 + quad * 8;
    const bf16* Brd = Bs + (wn * 64 + l16) * 32 + quad * 8;

    f32x4 acc[4][4];
    const f32x4 zero = {0.f, 0.f, 0.f, 0.f};
#pragma unroll
    for (int i = 0; i < 4; i++)
#pragma unroll
        for (int j = 0; j < 4; j++) acc[i][j] = zero;

    for (long k0 = k0beg; k0 < k0beg + ksp; k0 += KH * 32) {
        __syncthreads();
#pragma unroll
        for (int u = 0; u < 2; u++)
#pragma unroll
            for (int h = 0; h < KH; h++) {
                gload_lds16(gA[u][h] + k0, lA[u][h]);
                gload_lds16(gB[u][h] + k0, lB[u][h]);
            }
        __syncthreads();
#pragma unroll
        for (int h = 0; h < KH; h++) {
            short8 af[4], bfr[4];
#pragma unroll
            for (int mi = 0; mi < 4; mi++)
                af[mi] = *reinterpret_cast<const short8*>(Ard + h * TILE + mi * 16 * 32);
#pragma unroll
            for (int ni = 0; ni < 4; ni++)
                bfr[ni] = *reinterpret_cast<const short8*>(Brd + h * TILE + ni * 16 * 32);
#pragma unroll
            for (int mi = 0; mi < 4; mi++)
#pragma unroll
                for (int ni = 0; ni < 4; ni++)
                    acc[mi][ni] = __builtin_amdgcn_mfma_f32_16x16x32_bf16(af[mi], bfr[ni], acc[mi][ni], 0, 0, 0);
        }
    }

    // C/D layout (m89/m91): col = lane&15, row = quad*4 + r
    if (MODE == 0 || MODE == 1) {
        __syncthreads();  // tiles dead; reuse smem for epilogue staging
        bf16* eb = smem + wave * 1152;  // 16 rows x stride-72 bf16 = 2304 B / wave
        float bcol[4];
        if (MODE == 0) {
#pragma unroll
            for (int ni = 0; ni < 4; ni++) bcol[ni] = bias[bn0 + wn * 64 + l16 + ni * 16];
        }
#pragma unroll
        for (int mi = 0; mi < 4; mi++) {
#pragma unroll
            for (int r = 0; r < 4; r++) {
                float s = 0.f;
#pragma unroll
                for (int ni = 0; ni < 4; ni++) {
                    float v = acc[mi][ni][r];
                    if (MODE == 0) v += bcol[ni];
                    else { v = __expf(v * scale); s += v; }
                    eb[(quad * 4 + r) * 72 + ni * 16 + l16] = __float2bfloat16(v);
                }
                if (MODE == 1) {
                    s += __shfl_xor(s, 1);
                    s += __shfl_xor(s, 2);
                    s += __shfl_xor(s, 4);
                    s += __shfl_xor(s, 8);
                    if (l16 == 0) atomicAdd(&lsum[bm0 + wm * 64 + mi * 16 + quad * 4 + r], s);
                }
            }
            asm volatile("s_waitcnt lgkmcnt(0)" ::: "memory");
#pragma unroll
            for (int p = 0; p < 2; p++) {
                int r2 = p * 8 + (lane >> 3);
                int c2 = (lane & 7) * 8;
                short8 val = *reinterpret_cast<const short8*>(eb + r2 * 72 + c2);
                *reinterpret_cast<short8*>(
                    outb + (size_t)(bm0 + wm * 64 + mi * 16 + r2) * ldout + bn0 + wn * 64 + c2) = val;
            }
            asm volatile("s_waitcnt lgkmcnt(0)" ::: "memory");
        }
    } else {
        const int rb2 = wm * 64 + quad * 4;
        const int cb2 = wn * 64 + l16;
#pragma unroll
        for (int mi = 0; mi < 4; mi++)
#pragma unroll
            for (int r = 0; r < 4; r++) {
                long row = bm0 + rb2 + mi * 16 + r;
                float mul = (MODE == 3) ? 1.0f / lsum[row] : 0.f;
#pragma unroll
                for (int ni = 0; ni < 4; ni++) {
                    long col = bn0 + cb2 + ni * 16;
                    if (MODE == 3)      outf[row * ldout + col] = acc[mi][ni][r] * mul;
                    else if (MODE == 4) atomicAdd(&outf[row * ldout + col], acc[mi][ni][r]);
                    else                outf[row * ldout + col] += acc[mi][ni][r];
                }
            }
    }
}

extern "C" void kernel_launch(void* const* d_in, const int* in_sizes, int n_in,
                              void* d_out, int out_size, void* d_ws, size_t ws_size,
                              hipStream_t stream) {
    const float* feat = (const float*)d_in[0];
    const float* Wq   = (const float*)d_in[1];
    const float* bqv  = (const float*)d_in[2];
    const float* Wk   = (const float*)d_in[3];
    const float* bkv  = (const float*)d_in[4];
    const float* Wv   = (const float*)d_in[5];
    const float* bvv  = (const float*)d_in[6];
    float* outp = (float*)d_out;

    const int M = 8192, D = 1024;
    char* ws = (char*)d_ws;
    size_t off = 0;
    auto carve = [&](size_t bytes) -> char* {
        char* r = ws + off;
        off += (bytes + 255) & ~(size_t)255;
        return r;
    };
    bf16* featb = (bf16*)carve((size_t)M * D * 2);      // dead after QKV gemm
    bf16* Wbt   = (bf16*)carve((size_t)3 * D * D * 2);  // dead after QKV gemm
    bf16* qkv   = (bf16*)carve((size_t)3 * M * D * 2);  // q | k | v slabs
    float* lsum = (float*)carve((size_t)M * 4);
    bf16* vbt   = featb;  // v^T [D][M], aliases dead featb (tpose runs after QKV)
    size_t avail = (ws_size > off) ? ws_size - off : 0;

    int C;  // key-chunk width for P
    if      (avail >= (size_t)M * M * 2)    C = M;     // full P, 128 MB
    else if (avail >= (size_t)M * 4096 * 2) C = 4096;
    else if (avail >= (size_t)M * 2048 * 2) C = 2048;
    else                                    C = 1024;
    bf16* Pc = (bf16*)carve((size_t)M * C * 2);

    // 1) fused prep: feat->bf16, W transpose+cvt, lsum zero
    prep_kernel<<<dim3(11265), dim3(256), 0, stream>>>(
        feat, (unsigned short*)featb, Wq, Wk, Wv, Wbt, lsum);
    // 2) QKV projection, BK=64
    gemm_bt<0, 2, 0><<<dim3(M / 128, D / 128, 3), dim3(256), 0, stream>>>(
        featb, Wbt, bqv, bkv, bvv, nullptr, qkv, nullptr, M, D, D, D, D, 1.0f);
    // 3) v -> v^T
    tpose_bf16<<<dim3(D / 32, M / 32), dim3(32, 8), 0, stream>>>(qkv + (size_t)2 * M * D, vbt, M, D);

    const float scale = 0.03125f;  // 1/sqrt(1024)
    bf16* qb = qkv;
    bf16* kb = qkv + (size_t)M * D;
    if (C == M) {
        // 4a) full P = exp(q k^T/32): grid 64x64, BK=64
        gemm_bt<1, 2, 0><<<dim3(M / 128, M / 128), dim3(256), 0, stream>>>(
            qb, kb, nullptr, nullptr, nullptr, lsum, Pc, nullptr, M, M, D, D, M, scale);
        // 5a) out = P v, split-K x2 (z halves K), XCD-swizzled (8 x 64 x 2), atomic accum
        hipMemsetAsync(outp, 0, (size_t)M * D * 4, stream);
        gemm_bt<4, 2, 2><<<dim3(D / 128, M / 128, 2), dim3(256), 0, stream>>>(
            Pc, vbt, nullptr, nullptr, nullptr, nullptr, nullptr, outp, M, D, M, M, D, 0.f);
        // 6a) out /= rowsum
        scale_rows<<<dim3(M * D / 4 / 256), dim3(256), 0, stream>>>(outp, lsum);
    } else {
        hipMemsetAsync(outp, 0, (size_t)M * D * 4, stream);
        for (int c = 0; c < M / C; c++) {
            gemm_bt<1, 2, 0><<<dim3(M / 128, C / 128), dim3(256), 0, stream>>>(
                qb, kb + (size_t)c * C * D, nullptr, nullptr, nullptr, lsum, Pc, nullptr,
                M, C, D, D, C, scale);
            gemm_bt<2, 2, 1><<<dim3(D / 128, M / 128), dim3(256), 0, stream>>>(
                Pc, vbt + (size_t)c * C, nullptr, nullptr, nullptr, nullptr, nullptr, outp,
                M, D, C, M, D, 0.f);
        }
        scale_rows<<<dim3(M * D / 4 / 256), dim3(256), 0, stream>>>(outp, lsum);
    }
}

// Round 9
// 445.950 us; speedup vs baseline: 1.0676x; 1.0676x over previous
//
#include <hip/hip_runtime.h>
#include <hip/hip_bf16.h>
#include <stdint.h>

typedef __hip_bfloat16 bf16;
typedef __attribute__((ext_vector_type(8))) short short8;
typedef __attribute__((ext_vector_type(4))) float f32x4;

#define BM 128
#define BN 128

__device__ __forceinline__ unsigned short f2bf_bits(float x) {
    return __builtin_bit_cast(unsigned short, __float2bfloat16(x));
}

// async global->LDS, 16B per lane, LDS dest = wave-uniform base + lane*16
__device__ __forceinline__ void gload_lds16(const bf16* g, bf16* l) {
    __builtin_amdgcn_global_load_lds(
        (const __attribute__((address_space(1))) void*)(const void*)g,
        (__attribute__((address_space(3))) void*)(void*)l,
        16, 0, 0);
}

// fused prep: [0,8192) feat->bf16 cvt; [8192,11264) W transpose+cvt; [11264] zero lsum
__global__ void prep_kernel(const float* __restrict__ feat, unsigned short* __restrict__ featb,
                            const float* __restrict__ W0, const float* __restrict__ W1,
                            const float* __restrict__ W2, bf16* __restrict__ Wt,
                            float* __restrict__ lsum) {
    const int b = blockIdx.x;
    const int tid = threadIdx.x;
    if (b < 8192) {
        int i = b * 256 + tid;
        float4 v = reinterpret_cast<const float4*>(feat)[i];
        ushort4 o;
        o.x = f2bf_bits(v.x); o.y = f2bf_bits(v.y);
        o.z = f2bf_bits(v.z); o.w = f2bf_bits(v.w);
        reinterpret_cast<ushort4*>(featb)[i] = o;
    } else if (b < 11264) {
        __shared__ float tile[32][33];
        const int b2 = b - 8192;
        const int z = b2 >> 10;
        const int t = b2 & 1023;
        const int bx = t & 31, by = t >> 5;
        const int tx = tid & 31, ty = tid >> 5;
        const float* in = (z == 0) ? W0 : (z == 1) ? W1 : W2;
        bf16* out = Wt + (size_t)z * 1024 * 1024;
        for (int r = ty; r < 32; r += 8)
            tile[r][tx] = in[(size_t)(by * 32 + r) * 1024 + bx * 32 + tx];
        __syncthreads();
        for (int r = ty; r < 32; r += 8)
            out[(size_t)(bx * 32 + r) * 1024 + by * 32 + tx] = __float2bfloat16(tile[tx][r]);
    } else {
        for (int i = tid; i < 8192; i += 256) lsum[i] = 0.f;
    }
}

__global__ void scale_rows(float* __restrict__ out, const float* __restrict__ lsum) {
    int i = blockIdx.x * 256 + threadIdx.x;
    float4 v = reinterpret_cast<float4*>(out)[i];
    float inv = 1.0f / lsum[i >> 8];
    v.x *= inv; v.y *= inv; v.z *= inv; v.w *= inv;
    reinterpret_cast<float4*>(out)[i] = v;
}

// C[M][N] = A[M][K] * B[N][K]^T   (A row-stride = K, B row-stride = ldb)
// LDS tiles: KH stacked [128][32] half-tiles (64 B row stride, conflict-free b128).
// SWAP=1: blockIdx.x = N-tiles, blockIdx.y = M-tiles (chunked fallback O).
// SWAP=2: XCD-swizzled O grid (gridDim=(8, M/128)): 8 col-tile blocks sharing
//         one P row-slab map to consecutive slots of ONE XCD.
// MODE 0: outb = C + bias[col]  (q,k slabs via blockIdx.z), LDS-staged bf16 stores
// MODE 1: outb = exp(C*scale), atomicAdd row-sums -> lsum, LDS-staged stores
// MODE 2: outf += C                      (chunked O fallback)
// MODE 3: outf  = C / lsum[row]          (full-P O, single launch)
// MODE 5: outb = C + bias[row]           (direct v^T projection)
template <int MODE, int KH, int SWAP>
__global__ __launch_bounds__(256, 4)
void gemm_bt(const bf16* __restrict__ A, const bf16* __restrict__ B,
             const float* __restrict__ b0, const float* __restrict__ b1,
             const float* __restrict__ b2, float* __restrict__ lsum,
             bf16* __restrict__ outb, float* __restrict__ outf,
             int M, int N, int K, int ldb, int ldout, float scale) {
    constexpr int TILE = 128 * 32;
    constexpr int SELEMS = (2 * KH * TILE < 9216) ? 9216 : 2 * KH * TILE;
    __shared__ bf16 smem[SELEMS];
    bf16* As = smem;             // As + h*TILE
    bf16* Bs = smem + KH * TILE; // Bs + h*TILE

    const int tid  = threadIdx.x;
    const int lane = tid & 63;
    const int wave = tid >> 6;
    const int wm = wave & 1, wn = wave >> 1;
    const int l16  = lane & 15;
    const int quad = lane >> 4;
    long bm0, bn0;
    if (SWAP == 2) {
        const int lin = blockIdx.y * 8 + blockIdx.x;  // x fastest in dispatch order
        const int xcd = lin & 7;
        const int s   = lin >> 3;
        bn0 = (long)(s & 7) * BN;              // col tile 0..7
        bm0 = (long)((s >> 3) * 8 + xcd) * BM; // row tile, XCD-grouped
    } else {
        bm0 = (long)(SWAP ? blockIdx.y : blockIdx.x) * BM;
        bn0 = (long)(SWAP ? blockIdx.x : blockIdx.y) * BN;
    }

    const float* bias = nullptr;
    if (MODE == 0) {
        const int z = blockIdx.z;  // 0=q, 1=k
        B    += (size_t)z * N * K;
        outb += (size_t)z * M * ldout;
        bias  = (z == 0) ? b0 : b1;
    }

    // staging: per wave rows [wave*32, wave*32+32); u = 16-row slab, h = K-half.
    const int lrow = lane >> 2;
    const int lcol = (lane & 3) * 8;
    const bf16* gA[2][KH];
    const bf16* gB[2][KH];
    bf16* lA[2][KH];
    bf16* lB[2][KH];
#pragma unroll
    for (int u = 0; u < 2; u++)
#pragma unroll
        for (int h = 0; h < KH; h++) {
            gA[u][h] = A + (size_t)(bm0 + wave * 32 + u * 16 + lrow) * K + h * 32 + lcol;
            gB[u][h] = B + (size_t)(bn0 + wave * 32 + u * 16 + lrow) * ldb + h * 32 + lcol;
            lA[u][h] = As + h * TILE + (wave * 32 + u * 16) * 32;
            lB[u][h] = Bs + h * TILE + (wave * 32 + u * 16) * 32;
        }

    const bf16* Ard = As + (wm * 64 + l16) * 32 + quad * 8;
    const bf16* Brd = Bs + (wn * 64 + l16) * 32 + quad * 8;

    f32x4 acc[4][4];
    const f32x4 zero = {0.f, 0.f, 0.f, 0.f};
#pragma unroll
    for (int i = 0; i < 4; i++)
#pragma unroll
        for (int j = 0; j < 4; j++) acc[i][j] = zero;

    for (int k0 = 0; k0 < K; k0 += KH * 32) {
        __syncthreads();
#pragma unroll
        for (int u = 0; u < 2; u++)
#pragma unroll
            for (int h = 0; h < KH; h++) {
                gload_lds16(gA[u][h] + k0, lA[u][h]);
                gload_lds16(gB[u][h] + k0, lB[u][h]);
            }
        __syncthreads();
#pragma unroll
        for (int h = 0; h < KH; h++) {
            short8 af[4], bfr[4];
#pragma unroll
            for (int mi = 0; mi < 4; mi++)
                af[mi] = *reinterpret_cast<const short8*>(Ard + h * TILE + mi * 16 * 32);
#pragma unroll
            for (int ni = 0; ni < 4; ni++)
                bfr[ni] = *reinterpret_cast<const short8*>(Brd + h * TILE + ni * 16 * 32);
#pragma unroll
            for (int mi = 0; mi < 4; mi++)
#pragma unroll
                for (int ni = 0; ni < 4; ni++)
                    acc[mi][ni] = __builtin_amdgcn_mfma_f32_16x16x32_bf16(af[mi], bfr[ni], acc[mi][ni], 0, 0, 0);
        }
    }

    // C/D layout (m89/m91): col = lane&15, row = quad*4 + r
    if (MODE == 0 || MODE == 1 || MODE == 5) {
        __syncthreads();  // tiles dead; reuse smem for epilogue staging
        bf16* eb = smem + wave * 1152;  // 16 rows x stride-72 bf16 = 2304 B / wave
        float bcol[4];
        if (MODE == 0) {
#pragma unroll
            for (int ni = 0; ni < 4; ni++) bcol[ni] = bias[bn0 + wn * 64 + l16 + ni * 16];
        }
#pragma unroll
        for (int mi = 0; mi < 4; mi++) {
#pragma unroll
            for (int r = 0; r < 4; r++) {
                float s = 0.f;
                float brow = 0.f;
                if (MODE == 5) brow = b2[bm0 + wm * 64 + mi * 16 + quad * 4 + r];
#pragma unroll
                for (int ni = 0; ni < 4; ni++) {
                    float v = acc[mi][ni][r];
                    if (MODE == 0)      v += bcol[ni];
                    else if (MODE == 5) v += brow;
                    else { v = __expf(v * scale); s += v; }
                    eb[(quad * 4 + r) * 72 + ni * 16 + l16] = __float2bfloat16(v);
                }
                if (MODE == 1) {
                    s += __shfl_xor(s, 1);
                    s += __shfl_xor(s, 2);
                    s += __shfl_xor(s, 4);
                    s += __shfl_xor(s, 8);
                    if (l16 == 0) atomicAdd(&lsum[bm0 + wm * 64 + mi * 16 + quad * 4 + r], s);
                }
            }
            asm volatile("s_waitcnt lgkmcnt(0)" ::: "memory");
#pragma unroll
            for (int p = 0; p < 2; p++) {
                int r2 = p * 8 + (lane >> 3);
                int c2 = (lane & 7) * 8;
                short8 val = *reinterpret_cast<const short8*>(eb + r2 * 72 + c2);
                *reinterpret_cast<short8*>(
                    outb + (size_t)(bm0 + wm * 64 + mi * 16 + r2) * ldout + bn0 + wn * 64 + c2) = val;
            }
            asm volatile("s_waitcnt lgkmcnt(0)" ::: "memory");
        }
    } else {
        const int rb2 = wm * 64 + quad * 4;
        const int cb2 = wn * 64 + l16;
#pragma unroll
        for (int mi = 0; mi < 4; mi++)
#pragma unroll
            for (int r = 0; r < 4; r++) {
                long row = bm0 + rb2 + mi * 16 + r;
                float mul = (MODE == 3) ? 1.0f / lsum[row] : 0.f;
#pragma unroll
                for (int ni = 0; ni < 4; ni++) {
                    long col = bn0 + cb2 + ni * 16;
                    if (MODE == 3) outf[row * ldout + col] = acc[mi][ni][r] * mul;
                    else           outf[row * ldout + col] += acc[mi][ni][r];
                }
            }
    }
}

extern "C" void kernel_launch(void* const* d_in, const int* in_sizes, int n_in,
                              void* d_out, int out_size, void* d_ws, size_t ws_size,
                              hipStream_t stream) {
    const float* feat = (const float*)d_in[0];
    const float* Wq   = (const float*)d_in[1];
    const float* bqv  = (const float*)d_in[2];
    const float* Wk   = (const float*)d_in[3];
    const float* bkv  = (const float*)d_in[4];
    const float* Wv   = (const float*)d_in[5];
    const float* bvv  = (const float*)d_in[6];
    float* outp = (float*)d_out;

    const int M = 8192, D = 1024;
    char* ws = (char*)d_ws;
    size_t off = 0;
    auto carve = [&](size_t bytes) -> char* {
        char* r = ws + off;
        off += (bytes + 255) & ~(size_t)255;
        return r;
    };
    bf16* featb = (bf16*)carve((size_t)M * D * 2);      // stays live (vT gemm reads it)
    bf16* Wbt   = (bf16*)carve((size_t)3 * D * D * 2);
    bf16* qk    = (bf16*)carve((size_t)2 * M * D * 2);  // q | k slabs
    bf16* vbt   = (bf16*)carve((size_t)D * M * 2);      // v^T [D][M], produced directly
    float* lsum = (float*)carve((size_t)M * 4);
    size_t avail = (ws_size > off) ? ws_size - off : 0;

    int C;  // key-chunk width for P
    if      (avail >= (size_t)M * M * 2)    C = M;     // full P, 128 MB
    else if (avail >= (size_t)M * 4096 * 2) C = 4096;
    else if (avail >= (size_t)M * 2048 * 2) C = 2048;
    else                                    C = 1024;
    bf16* Pc = (bf16*)carve((size_t)M * C * 2);

    // 1) fused prep: feat->bf16, W transpose+cvt, lsum zero
    prep_kernel<<<dim3(11265), dim3(256), 0, stream>>>(
        feat, (unsigned short*)featb, Wq, Wk, Wv, Wbt, lsum);
    // 2) q,k projection (z = 0,1), BK=64
    gemm_bt<0, 2, 0><<<dim3(M / 128, D / 128, 2), dim3(256), 0, stream>>>(
        featb, Wbt, bqv, bkv, nullptr, nullptr, qk, nullptr, M, D, D, D, D, 1.0f);
    // 3) v^T directly: vT[d][m] = sum_k WbtV[d][k]*featb[m][k] + bv[d]
    gemm_bt<5, 2, 0><<<dim3(D / 128, M / 128), dim3(256), 0, stream>>>(
        Wbt + (size_t)2 * D * D, featb, nullptr, nullptr, bvv, nullptr, vbt, nullptr,
        D, M, D, D, M, 1.0f);

    const float scale = 0.03125f;  // 1/sqrt(1024)
    bf16* qb = qk;
    bf16* kb = qk + (size_t)M * D;
    if (C == M) {
        // 4a) full P = exp(q k^T/32): grid 64x64, BK=64
        gemm_bt<1, 2, 0><<<dim3(M / 128, M / 128), dim3(256), 0, stream>>>(
            qb, kb, nullptr, nullptr, nullptr, lsum, Pc, nullptr, M, M, D, D, M, scale);
        // 5a) out = (P v) / lsum, K=8192, BK=64, XCD-swizzled grid (8 x 64)
        gemm_bt<3, 2, 2><<<dim3(D / 128, M / 128), dim3(256), 0, stream>>>(
            Pc, vbt, nullptr, nullptr, nullptr, lsum, nullptr, outp, M, D, M, M, D, 0.f);
    } else {
        hipMemsetAsync(outp, 0, (size_t)M * D * 4, stream);
        for (int c = 0; c < M / C; c++) {
            gemm_bt<1, 2, 0><<<dim3(M / 128, C / 128), dim3(256), 0, stream>>>(
                qb, kb + (size_t)c * C * D, nullptr, nullptr, nullptr, lsum, Pc, nullptr,
                M, C, D, D, C, scale);
            gemm_bt<2, 2, 1><<<dim3(D / 128, M / 128), dim3(256), 0, stream>>>(
                Pc, vbt + (size_t)c * C, nullptr, nullptr, nullptr, nullptr, nullptr, outp,
                M, D, C, M, D, 0.f);
        }
        scale_rows<<<dim3(M * D / 4 / 256), dim3(256), 0, stream>>>(outp, lsum);
    }
}

// Round 10
// 439.404 us; speedup vs baseline: 1.0835x; 1.0149x over previous
//
#include <hip/hip_runtime.h>
#include <hip/hip_bf16.h>
#include <stdint.h>

typedef __hip_bfloat16 bf16;
typedef __attribute__((ext_vector_type(8))) short short8;
typedef __attribute__((ext_vector_type(4))) float f32x4;

#define BM 128
#define BN 128

__device__ __forceinline__ unsigned short f2bf_bits(float x) {
    return __builtin_bit_cast(unsigned short, __float2bfloat16(x));
}

// async global->LDS, 16B per lane, LDS dest = wave-uniform base + lane*16
__device__ __forceinline__ void gload_lds16(const bf16* g, bf16* l) {
    __builtin_amdgcn_global_load_lds(
        (const __attribute__((address_space(1))) void*)(const void*)g,
        (__attribute__((address_space(3))) void*)(void*)l,
        16, 0, 0);
}

// fused prep: [0,8192) feat->bf16 cvt; [8192,11264) W transpose+cvt; [11264] zero lsum
__global__ void prep_kernel(const float* __restrict__ feat, unsigned short* __restrict__ featb,
                            const float* __restrict__ W0, const float* __restrict__ W1,
                            const float* __restrict__ W2, bf16* __restrict__ Wt,
                            float* __restrict__ lsum) {
    const int b = blockIdx.x;
    const int tid = threadIdx.x;
    if (b < 8192) {
        int i = b * 256 + tid;
        float4 v = reinterpret_cast<const float4*>(feat)[i];
        ushort4 o;
        o.x = f2bf_bits(v.x); o.y = f2bf_bits(v.y);
        o.z = f2bf_bits(v.z); o.w = f2bf_bits(v.w);
        reinterpret_cast<ushort4*>(featb)[i] = o;
    } else if (b < 11264) {
        __shared__ float tile[32][33];
        const int b2 = b - 8192;
        const int z = b2 >> 10;
        const int t = b2 & 1023;
        const int bx = t & 31, by = t >> 5;
        const int tx = tid & 31, ty = tid >> 5;
        const float* in = (z == 0) ? W0 : (z == 1) ? W1 : W2;
        bf16* out = Wt + (size_t)z * 1024 * 1024;
        for (int r = ty; r < 32; r += 8)
            tile[r][tx] = in[(size_t)(by * 32 + r) * 1024 + bx * 32 + tx];
        __syncthreads();
        for (int r = ty; r < 32; r += 8)
            out[(size_t)(bx * 32 + r) * 1024 + by * 32 + tx] = __float2bfloat16(tile[tx][r]);
    } else {
        for (int i = tid; i < 8192; i += 256) lsum[i] = 0.f;
    }
}

__global__ void scale_rows(float* __restrict__ out, const float* __restrict__ lsum) {
    int i = blockIdx.x * 256 + threadIdx.x;
    float4 v = reinterpret_cast<float4*>(out)[i];
    float inv = 1.0f / lsum[i >> 8];
    v.x *= inv; v.y *= inv; v.z *= inv; v.w *= inv;
    reinterpret_cast<float4*>(out)[i] = v;
}

// C[M][N] = A[M][K] * B[N][K]^T   (A row-stride = K, B row-stride = ldb)
// LDS tiles: KH stacked [128][32] half-tiles (64 B row stride, conflict-free b128).
// SWAP=1: blockIdx.x = N-tiles, blockIdx.y = M-tiles (chunked fallback O).
// SWAP=2: XCD-swizzled O grid (gridDim=(8, M/128)): 8 col-tile blocks sharing
//         one P row-slab map to consecutive slots of ONE XCD.
// MODE 0: merged projection. grid (M/128, N/128, 3).
//         z<2 : outb[z] = featb·Wbt[z]^T + bias_col   (q,k slabs)
//         z==2: vbt     = Wv^T·featb^T + bias_row     (direct v^T; out slab
//               contiguous after q|k at outb + 2*M*ldout, ld = M)
// MODE 1: outb = exp(C*scale), atomicAdd row-sums -> lsum, LDS-staged stores
// MODE 2: outf += C                      (chunked O fallback)
// MODE 3: outf  = C / lsum[row]          (full-P O, single launch)
template <int MODE, int KH, int SWAP>
__global__ __launch_bounds__(256, 4)
void gemm_bt(const bf16* __restrict__ A, const bf16* __restrict__ B,
             const float* __restrict__ b0, const float* __restrict__ b1,
             const float* __restrict__ b2, float* __restrict__ lsum,
             bf16* __restrict__ outb, float* __restrict__ outf,
             int M, int N, int K, int ldb, int ldout, float scale) {
    constexpr int TILE = 128 * 32;
    constexpr int SELEMS = (2 * KH * TILE < 9216) ? 9216 : 2 * KH * TILE;
    __shared__ bf16 smem[SELEMS];
    bf16* As = smem;             // As + h*TILE
    bf16* Bs = smem + KH * TILE; // Bs + h*TILE

    const int tid  = threadIdx.x;
    const int lane = tid & 63;
    const int wave = tid >> 6;
    const int wm = wave & 1, wn = wave >> 1;
    const int l16  = lane & 15;
    const int quad = lane >> 4;
    long bm0, bn0;
    if (SWAP == 2) {
        const int lin = blockIdx.y * 8 + blockIdx.x;  // x fastest in dispatch order
        const int xcd = lin & 7;
        const int s   = lin >> 3;
        bn0 = (long)(s & 7) * BN;              // col tile 0..7
        bm0 = (long)((s >> 3) * 8 + xcd) * BM; // row tile, XCD-grouped
    } else {
        bm0 = (long)(SWAP ? blockIdx.y : blockIdx.x) * BM;
        bn0 = (long)(SWAP ? blockIdx.x : blockIdx.y) * BN;
    }

    const bf16* Ause = A;
    const bf16* Buse = B;
    bf16* oz = outb;
    int  ldo = ldout;
    int  z   = 0;
    if (MODE == 0) {
        z = blockIdx.z;
        if (z == 2) {
            // v^T orientation: rows = D (N-dim of grid.y), cols = M samples
            bm0  = (long)blockIdx.y * BM;       // 0..N/128
            bn0  = (long)blockIdx.x * BN;       // 0..M/128
            Ause = B + (size_t)2 * N * K;       // Wv^T [N][K]
            Buse = A;                           // featb [M][K]
            oz   = outb + (size_t)2 * M * ldout; // vbt slab
            ldo  = M;
        } else {
            Buse = B + (size_t)z * N * K;
            oz   = outb + (size_t)z * M * ldout;
        }
    }

    // staging: per wave rows [wave*32, wave*32+32); u = 16-row slab, h = K-half.
    const int lrow = lane >> 2;
    const int lcol = (lane & 3) * 8;
    const bf16* gA[2][KH];
    const bf16* gB[2][KH];
    bf16* lA[2][KH];
    bf16* lB[2][KH];
#pragma unroll
    for (int u = 0; u < 2; u++)
#pragma unroll
        for (int h = 0; h < KH; h++) {
            gA[u][h] = Ause + (size_t)(bm0 + wave * 32 + u * 16 + lrow) * K + h * 32 + lcol;
            gB[u][h] = Buse + (size_t)(bn0 + wave * 32 + u * 16 + lrow) * ldb + h * 32 + lcol;
            lA[u][h] = As + h * TILE + (wave * 32 + u * 16) * 32;
            lB[u][h] = Bs + h * TILE + (wave * 32 + u * 16) * 32;
        }

    const bf16* Ard = As + (wm * 64 + l16) * 32 + quad * 8;
    const bf16* Brd = Bs + (wn * 64 + l16) * 32 + quad * 8;

    f32x4 acc[4][4];
    const f32x4 zero = {0.f, 0.f, 0.f, 0.f};
#pragma unroll
    for (int i = 0; i < 4; i++)
#pragma unroll
        for (int j = 0; j < 4; j++) acc[i][j] = zero;

    for (int k0 = 0; k0 < K; k0 += KH * 32) {
        __syncthreads();
#pragma unroll
        for (int u = 0; u < 2; u++)
#pragma unroll
            for (int h = 0; h < KH; h++) {
                gload_lds16(gA[u][h] + k0, lA[u][h]);
                gload_lds16(gB[u][h] + k0, lB[u][h]);
            }
        __syncthreads();
#pragma unroll
        for (int h = 0; h < KH; h++) {
            short8 af[4], bfr[4];
#pragma unroll
            for (int mi = 0; mi < 4; mi++)
                af[mi] = *reinterpret_cast<const short8*>(Ard + h * TILE + mi * 16 * 32);
#pragma unroll
            for (int ni = 0; ni < 4; ni++)
                bfr[ni] = *reinterpret_cast<const short8*>(Brd + h * TILE + ni * 16 * 32);
#pragma unroll
            for (int mi = 0; mi < 4; mi++)
#pragma unroll
                for (int ni = 0; ni < 4; ni++)
                    acc[mi][ni] = __builtin_amdgcn_mfma_f32_16x16x32_bf16(af[mi], bfr[ni], acc[mi][ni], 0, 0, 0);
        }
    }

    // C/D layout (m89/m91): col = lane&15, row = quad*4 + r
    if (MODE == 0 || MODE == 1) {
        __syncthreads();  // tiles dead; reuse smem for epilogue staging
        // double-buffered staging: 2 x 1152 elems per wave, alternate per mi slice
        float bcol[4];
        if (MODE == 0 && z < 2) {
            const float* bias = (z == 0) ? b0 : b1;
#pragma unroll
            for (int ni = 0; ni < 4; ni++) bcol[ni] = bias[bn0 + wn * 64 + l16 + ni * 16];
        }
#pragma unroll
        for (int mi = 0; mi < 4; mi++) {
            bf16* eb = smem + ((wave << 1) | (mi & 1)) * 1152;
#pragma unroll
            for (int r = 0; r < 4; r++) {
                float s = 0.f;
                float brow = 0.f;
                if (MODE == 0 && z == 2) brow = b2[bm0 + wm * 64 + mi * 16 + quad * 4 + r];
#pragma unroll
                for (int ni = 0; ni < 4; ni++) {
                    float v = acc[mi][ni][r];
                    if (MODE == 0) v += (z == 2) ? brow : bcol[ni];
                    else { v = __expf(v * scale); s += v; }
                    eb[(quad * 4 + r) * 72 + ni * 16 + l16] = __float2bfloat16(v);
                }
                if (MODE == 1) {
                    s += __shfl_xor(s, 1);
                    s += __shfl_xor(s, 2);
                    s += __shfl_xor(s, 4);
                    s += __shfl_xor(s, 8);
                    if (l16 == 0) atomicAdd(&lsum[bm0 + wm * 64 + mi * 16 + quad * 4 + r], s);
                }
            }
            // one wait per slice: drains this slice's writes AND the previous
            // slice's reads (other buffer), so mi+2 can't overwrite live data
            asm volatile("s_waitcnt lgkmcnt(0)" ::: "memory");
#pragma unroll
            for (int p = 0; p < 2; p++) {
                int r2 = p * 8 + (lane >> 3);
                int c2 = (lane & 7) * 8;
                short8 val = *reinterpret_cast<const short8*>(eb + r2 * 72 + c2);
                *reinterpret_cast<short8*>(
                    oz + (size_t)(bm0 + wm * 64 + mi * 16 + r2) * ldo + bn0 + wn * 64 + c2) = val;
            }
        }
    } else {
        const int rb2 = wm * 64 + quad * 4;
        const int cb2 = wn * 64 + l16;
#pragma unroll
        for (int mi = 0; mi < 4; mi++)
#pragma unroll
            for (int r = 0; r < 4; r++) {
                long row = bm0 + rb2 + mi * 16 + r;
                float mul = (MODE == 3) ? 1.0f / lsum[row] : 0.f;
#pragma unroll
                for (int ni = 0; ni < 4; ni++) {
                    long col = bn0 + cb2 + ni * 16;
                    if (MODE == 3) outf[row * ldout + col] = acc[mi][ni][r] * mul;
                    else           outf[row * ldout + col] += acc[mi][ni][r];
                }
            }
    }
}

extern "C" void kernel_launch(void* const* d_in, const int* in_sizes, int n_in,
                              void* d_out, int out_size, void* d_ws, size_t ws_size,
                              hipStream_t stream) {
    const float* feat = (const float*)d_in[0];
    const float* Wq   = (const float*)d_in[1];
    const float* bqv  = (const float*)d_in[2];
    const float* Wk   = (const float*)d_in[3];
    const float* bkv  = (const float*)d_in[4];
    const float* Wv   = (const float*)d_in[5];
    const float* bvv  = (const float*)d_in[6];
    float* outp = (float*)d_out;

    const int M = 8192, D = 1024;
    char* ws = (char*)d_ws;
    size_t off = 0;
    auto carve = [&](size_t bytes) -> char* {
        char* r = ws + off;
        off += (bytes + 255) & ~(size_t)255;
        return r;
    };
    bf16* featb = (bf16*)carve((size_t)M * D * 2);
    bf16* Wbt   = (bf16*)carve((size_t)3 * D * D * 2);
    // q | k | v^T contiguous: merged projection writes vbt at qk + 2*M*D
    bf16* qk    = (bf16*)carve((size_t)2 * M * D * 2 + (size_t)D * M * 2);
    bf16* vbt   = qk + (size_t)2 * M * D;
    float* lsum = (float*)carve((size_t)M * 4);
    size_t avail = (ws_size > off) ? ws_size - off : 0;

    int C;  // key-chunk width for P
    if      (avail >= (size_t)M * M * 2)    C = M;     // full P, 128 MB
    else if (avail >= (size_t)M * 4096 * 2) C = 4096;
    else if (avail >= (size_t)M * 2048 * 2) C = 2048;
    else                                    C = 1024;
    bf16* Pc = (bf16*)carve((size_t)M * C * 2);

    // 1) fused prep: feat->bf16, W transpose+cvt, lsum zero
    prep_kernel<<<dim3(11265), dim3(256), 0, stream>>>(
        feat, (unsigned short*)featb, Wq, Wk, Wv, Wbt, lsum);
    // 2) merged projection: z=0,1 -> q,k; z=2 -> v^T directly (BK=64)
    gemm_bt<0, 2, 0><<<dim3(M / 128, D / 128, 3), dim3(256), 0, stream>>>(
        featb, Wbt, bqv, bkv, bvv, nullptr, qk, nullptr, M, D, D, D, D, 1.0f);

    const float scale = 0.03125f;  // 1/sqrt(1024)
    bf16* qb = qk;
    bf16* kb = qk + (size_t)M * D;
    if (C == M) {
        // 3a) full P = exp(q k^T/32): grid 64x64, BK=64
        gemm_bt<1, 2, 0><<<dim3(M / 128, M / 128), dim3(256), 0, stream>>>(
            qb, kb, nullptr, nullptr, nullptr, lsum, Pc, nullptr, M, M, D, D, M, scale);
        // 4a) out = (P v) / lsum, K=8192, BK=64, XCD-swizzled grid (8 x 64)
        gemm_bt<3, 2, 2><<<dim3(D / 128, M / 128), dim3(256), 0, stream>>>(
            Pc, vbt, nullptr, nullptr, nullptr, lsum, nullptr, outp, M, D, M, M, D, 0.f);
    } else {
        hipMemsetAsync(outp, 0, (size_t)M * D * 4, stream);
        for (int c = 0; c < M / C; c++) {
            gemm_bt<1, 2, 0><<<dim3(M / 128, C / 128), dim3(256), 0, stream>>>(
                qb, kb + (size_t)c * C * D, nullptr, nullptr, nullptr, lsum, Pc, nullptr,
                M, C, D, D, C, scale);
            gemm_bt<2, 2, 1><<<dim3(D / 128, M / 128), dim3(256), 0, stream>>>(
                Pc, vbt + (size_t)c * C, nullptr, nullptr, nullptr, nullptr, nullptr, outp,
                M, D, C, M, D, 0.f);
        }
        scale_rows<<<dim3(M * D / 4 / 256), dim3(256), 0, stream>>>(outp, lsum);
    }
}